// Round 1
// baseline (718.938 us; speedup 1.0000x reference)
//
#include <hip/hip_runtime.h>
#include <math.h>

#define N_NODES 100000
#define N_EDGES 1600000
#define NODE_F  64
#define IN_DIM  160          // 2*64 + 32
#define N_TILES 25000        // N_EDGES / 64
#define ZSTRIDE 168          // bf16 elems per z-row in LDS (336 B, 16B-aligned)
#define EDGE_GRID 1792       // 7 blocks/CU

typedef __attribute__((ext_vector_type(8))) short short8;   // 8 bf16 = 4 VGPRs
typedef __attribute__((ext_vector_type(4))) float f32x4;

// round-to-nearest-even f32 -> bf16 bits (scalar; used only in W staging)
static __device__ inline unsigned short f2bf(float f) {
    union { float f; unsigned u; } v; v.f = f;
    unsigned r = v.u + 0x7fffu + ((v.u >> 16) & 1u);
    return (unsigned short)(r >> 16);
}

// RNE-round two f32 and pack their high halves into one dword:
// per float: round-bias add; then one v_perm_b32 grabs both high16s.
static __device__ inline unsigned pack2(float lo, float hi) {
    union { float f; unsigned u; } a, b; a.f = lo; b.f = hi;
    const unsigned ra = a.u + 0x7fffu + ((a.u >> 16) & 1u);
    const unsigned rb = b.u + 0x7fffu + ((b.u >> 16) & 1u);
    // result byte0,1 = ra bytes 2,3 ; byte2,3 = rb bytes 2,3
    return __builtin_amdgcn_perm(rb, ra, 0x07060302u);
}

// Barrier WITHOUT the vmcnt(0) drain __syncthreads() would emit.
// LDS coherence across the barrier needs only lgkmcnt(0); outstanding
// global atomics (fire-and-forget to msg) and the next-tile index
// prefetch stay in flight across tiles. "memory" clobber + sched_barrier
// pin all memory ops on their side of the fence (guide rule 18).
static __device__ __forceinline__ void tile_barrier() {
    __builtin_amdgcn_sched_barrier(0);
    asm volatile("s_waitcnt lgkmcnt(0)" ::: "memory");
    __builtin_amdgcn_s_barrier();
    __builtin_amdgcn_sched_barrier(0);
}

// ---------------------------------------------------------------------------
// Phase 1: gather f32 node rows -> bf16 z-tile in LDS -> MFMA gated MLP ->
// atomic scatter. Block = 256 thr (4 waves), 64 edges/tile. Wave w owns
// features [16w,16w+16) of both matrices; W frags in registers (loaded once
// per block). Tile edge indices live in registers, distributed via __shfl;
// next tile's indices are prefetched to hide gather-index latency.
// ---------------------------------------------------------------------------
__global__ __launch_bounds__(256, 7) void edge_kernel(
    const float* __restrict__ node_attrs,
    const int*   __restrict__ edge_src,
    const int*   __restrict__ edge_tgt,
    const float* __restrict__ edge_attrs,
    const float* __restrict__ W_f, const float* __restrict__ b_f,
    const float* __restrict__ W_s, const float* __restrict__ b_s,
    float* __restrict__ msg)
{
    __shared__ __align__(16) short sbuf[64 * ZSTRIDE];   // 21504 B
    unsigned* sbuf32 = (unsigned*)sbuf;

    const int tid  = threadIdx.x;
    const int wave = tid >> 6;
    const int lane = tid & 63;
    const int quad = lane >> 4;       // 0..3
    const int l15  = lane & 15;

    // ---- Stage W_f then W_s transposed to LDS, pull B-fragments to registers.
    short8 bF[5], bS[5];
#pragma unroll
    for (int mat = 0; mat < 2; ++mat) {
        const float* W = mat ? W_s : W_f;
        __syncthreads();
        for (int idx = tid; idx < IN_DIM * 64; idx += 256) {
            const int k = idx >> 6, n = idx & 63;
            sbuf[n * ZSTRIDE + k] = (short)f2bf(W[idx]);
        }
        __syncthreads();
#pragma unroll
        for (int kc = 0; kc < 5; ++kc) {
            const short8 b = *(const short8*)&sbuf[(16 * wave + l15) * ZSTRIDE + kc * 32 + quad * 8];
            if (mat) bS[kc] = b; else bF[kc] = b;
        }
    }

    const float bias_f = b_f[16 * wave + l15];
    const float bias_s = b_s[16 * wave + l15];
    float* const msgf  = msg + 16 * wave + l15;   // per-lane feature column

    // Prefetch first tile's indices.
    int srcv = edge_src[blockIdx.x * 64 + lane];
    int tgtv = edge_tgt[blockIdx.x * 64 + lane];

    for (int t = blockIdx.x; t < N_TILES; t += EDGE_GRID) {
        const int e0 = t * 64;

        tile_barrier();   // protect sbuf from previous iteration's readers
                          // (lgkm only -- epilogue atomics stay in flight)

        // ---- Node rows (f32 -> bf16 inline): wave w stages edges [16w,16w+16).
        // iter i: 4 row-halves; half = quad&1 (0=src,1=tgt), el = i*2+(quad>>1).
#pragma unroll
        for (int i = 0; i < 8; ++i) {
            const int el   = i * 2 + (quad >> 1);
            const int half = quad & 1;
            const int sl   = 16 * wave + el;
            const int ns   = __shfl(srcv, sl);
            const int nt   = __shfl(tgtv, sl);
            const int node = half ? nt : ns;
            const float4 v = *(const float4*)&node_attrs[node * 64 + l15 * 4];
            uint2 o; o.x = pack2(v.x, v.y); o.y = pack2(v.z, v.w);
            *(uint2*)&sbuf32[sl * (ZSTRIDE / 2) + half * 32 + l15 * 2] = o;
        }
        // ---- Edge attrs (f32 -> bf16 inline): 2 iters x 4 floats/thread... (8 total)
#pragma unroll
        for (int i = 0; i < 2; ++i) {
            const int p  = i * 256 + tid;       // 0..511
            const int el = p >> 3, g = p & 7;
            const float4 v = *(const float4*)&edge_attrs[(size_t)(e0 + el) * 32 + g * 4];
            uint2 o; o.x = pack2(v.x, v.y); o.y = pack2(v.z, v.w);
            *(uint2*)&sbuf32[el * (ZSTRIDE / 2) + 64 + g * 2] = o;
        }

        // Prefetch next tile's indices (now genuinely overlaps the MFMA
        // section: the barrier below no longer drains vmcnt).
        const int tn = t + EDGE_GRID;
        int nsrc = 0, ntgt = 0;
        if (tn < N_TILES) {
            nsrc = edge_src[tn * 64 + lane];
            ntgt = edge_tgt[tn * 64 + lane];
        }
        tile_barrier();   // staging ds_writes visible to all waves

        // ---- MFMA: 4 m-tiles x 5 k-chunks x 2 matrices, then fused epilogue.
#pragma unroll
        for (int mt = 0; mt < 4; ++mt) {
            f32x4 accF = {0.f, 0.f, 0.f, 0.f};
            f32x4 accS = {0.f, 0.f, 0.f, 0.f};
#pragma unroll
            for (int kc = 0; kc < 5; ++kc) {
                const short8 a = *(const short8*)&sbuf[(mt * 16 + l15) * ZSTRIDE + kc * 32 + quad * 8];
                accF = __builtin_amdgcn_mfma_f32_16x16x32_bf16(a, bF[kc], accF, 0, 0, 0);
                accS = __builtin_amdgcn_mfma_f32_16x16x32_bf16(a, bS[kc], accS, 0, 0, 0);
            }
            // C/D: col = l15 (feature), row = quad*4 + r (edge within m-tile)
#pragma unroll
            for (int r = 0; r < 4; ++r) {
                const float xf = accF[r] + bias_f;
                const float xs = accS[r] + bias_s;
                const float sig = __builtin_amdgcn_rcpf(1.0f + __expf(-xf));
                const float sp  = fmaxf(xs, 0.0f) + __logf(1.0f + __expf(-fabsf(xs)));
                const float h   = sig * sp;
                const int sl    = mt * 16 + quad * 4 + r;   // edge within tile
                const int node  = __shfl(srcv, sl);
                atomicAdd(&msgf[node * 64], h);   // fire-and-forget; never
                                                  // waited on inside the loop
            }
        }

        srcv = nsrc;
        tgtv = ntgt;
    }
}

// ---------------------------------------------------------------------------
// Phase 2: per-feature sum / sumsq over nodes (BatchNorm batch stats).
// 1024 blocks (4/CU), float4 loads: block covers 16 rows x 16 f4-groups
// per iteration (4 KB contiguous), ~6 iterations/thread. LDS reduce
// across the 16 rows, then 8 atomics per finalizer thread.
// ---------------------------------------------------------------------------
#define STATS_BLOCKS 1024
__global__ __launch_bounds__(256) void stats_kernel(
    const float* __restrict__ msg, float* __restrict__ stats)
{
    const int tid = threadIdx.x;
    const int g4  = tid & 15;        // feature group: features g4*4 .. g4*4+3
    const int r0  = tid >> 4;        // 0..15 row-within-block
    float4 s = {0.f, 0.f, 0.f, 0.f};
    float4 q = {0.f, 0.f, 0.f, 0.f};
    for (int r = blockIdx.x * 16 + r0; r < N_NODES; r += STATS_BLOCKS * 16) {
        const float4 v = *(const float4*)&msg[(size_t)r * 64 + g4 * 4];
        s.x += v.x; s.y += v.y; s.z += v.z; s.w += v.w;
        q.x = fmaf(v.x, v.x, q.x);
        q.y = fmaf(v.y, v.y, q.y);
        q.z = fmaf(v.z, v.z, q.z);
        q.w = fmaf(v.w, v.w, q.w);
    }
    __shared__ float4 rs[256];
    __shared__ float4 rq[256];
    rs[tid] = s;
    rq[tid] = q;
    __syncthreads();
    if (tid < 16) {
        float4 S = rs[tid];
        float4 Q = rq[tid];
        for (int k = 1; k < 16; ++k) {
            const float4 a = rs[k * 16 + tid];
            const float4 b = rq[k * 16 + tid];
            S.x += a.x; S.y += a.y; S.z += a.z; S.w += a.w;
            Q.x += b.x; Q.y += b.y; Q.z += b.z; Q.w += b.w;
        }
        atomicAdd(&stats[tid * 4 + 0], S.x);
        atomicAdd(&stats[tid * 4 + 1], S.y);
        atomicAdd(&stats[tid * 4 + 2], S.z);
        atomicAdd(&stats[tid * 4 + 3], S.w);
        atomicAdd(&stats[64 + tid * 4 + 0], Q.x);
        atomicAdd(&stats[64 + tid * 4 + 1], Q.y);
        atomicAdd(&stats[64 + tid * 4 + 2], Q.z);
        atomicAdd(&stats[64 + tid * 4 + 3], Q.w);
    }
}

// ---------------------------------------------------------------------------
// Phase 3: in-place BN (training stats, biased var) + residual.
// ---------------------------------------------------------------------------
__global__ __launch_bounds__(256) void norm_kernel(
    const float* __restrict__ node_attrs,
    const float* __restrict__ stats,
    const float* __restrict__ gamma,
    const float* __restrict__ beta,
    float* __restrict__ out)
{
    const int i = blockIdx.x * blockDim.x + threadIdx.x;
    const int idx = i * 4;
    if (idx >= N_NODES * 64) return;
    const int f = idx & 63;
    const float inv_n = 1.0f / (float)N_NODES;

    const float4 m4 = *(const float4*)&out[idx];
    const float4 x4 = *(const float4*)&node_attrs[idx];

    float mean[4], rstd[4], gm[4], bt[4];
#pragma unroll
    for (int j = 0; j < 4; ++j) {
        mean[j] = stats[f + j] * inv_n;
        const float var = stats[64 + f + j] * inv_n - mean[j] * mean[j];
        rstd[j] = rsqrtf(var + 1e-5f);
        gm[j] = gamma[f + j];
        bt[j] = beta[f + j];
    }
    float4 o;
    o.x = x4.x + (m4.x - mean[0]) * rstd[0] * gm[0] + bt[0];
    o.y = x4.y + (m4.y - mean[1]) * rstd[1] * gm[1] + bt[1];
    o.z = x4.z + (m4.z - mean[2]) * rstd[2] * gm[2] + bt[2];
    o.w = x4.w + (m4.w - mean[3]) * rstd[3] * gm[3] + bt[3];
    *(float4*)&out[idx] = o;
}

extern "C" void kernel_launch(void* const* d_in, const int* in_sizes, int n_in,
                              void* d_out, int out_size, void* d_ws, size_t ws_size,
                              hipStream_t stream)
{
    const float* node_attrs = (const float*)d_in[0];
    const int*   edge_index = (const int*)d_in[1];   // [2, E] int32
    const float* edge_attrs = (const float*)d_in[2];
    const float* W_f   = (const float*)d_in[3];
    const float* b_f   = (const float*)d_in[4];
    const float* W_s   = (const float*)d_in[5];
    const float* b_s   = (const float*)d_in[6];
    const float* gamma = (const float*)d_in[7];
    const float* beta  = (const float*)d_in[8];

    float* out   = (float*)d_out;          // doubles as the msg accumulator
    float* stats = (float*)d_ws;           // 128 floats (512 B of ws only)

    const int* edge_src = edge_index;
    const int* edge_tgt = edge_index + N_EDGES;

    hipMemsetAsync(out, 0, (size_t)N_NODES * NODE_F * sizeof(float), stream);
    hipMemsetAsync(stats, 0, 128 * sizeof(float), stream);

    edge_kernel<<<EDGE_GRID, 256, 0, stream>>>(
        node_attrs, edge_src, edge_tgt, edge_attrs, W_f, b_f, W_s, b_s, out);

    stats_kernel<<<STATS_BLOCKS, 256, 0, stream>>>(out, stats);

    norm_kernel<<<(N_NODES * NODE_F / 4 + 255) / 256, 256, 0, stream>>>(
        node_attrs, stats, gamma, beta, out);
}